// Round 1
// baseline (230.029 us; speedup 1.0000x reference)
//
#include <hip/hip_runtime.h>

#define B_    16
#define N_    65536
#define C_    256
#define DIN_  16
#define DOUT_ 16
#define RATIO_ 256  // N_/C_

// workspace layout (floats):
//   s    [DIN_][B_][C_]   = 65536 floats  (s[i][b][k])
//   off  [B_][C_][DOUT_]  = 65536 floats  (includes /N and +b1)
//   wd_t [C_][DIN_][DOUT_]= 65536 floats  (w_diag transposed per cluster)

// ---------------------------------------------------------------------------
// Kernel A: cluster sums s[b,k,i] = sum_r x[b, P[k*256+r], i]
// grid = B_*C_ blocks (b,k) + C_ extra blocks doing the w_diag transpose.
// ---------------------------------------------------------------------------
__global__ __launch_bounds__(256) void k_cluster_sum(
    const float* __restrict__ x, const float* __restrict__ w_diag,
    const int* __restrict__ P, float* __restrict__ s, float* __restrict__ wd_t)
{
    int bid = blockIdx.x;
    int t = threadIdx.x;
    if (bid >= B_ * C_) {
        // transpose w_diag[o][i][c] -> wd_t[c][i*16+o]
        int c = bid - B_ * C_;
        int i = t >> 4, o = t & 15;
        wd_t[c * 256 + t] = w_diag[(o * DIN_ + i) * C_ + c];
        return;
    }
    int b = bid >> 8;       // /C_
    int k = bid & (C_ - 1);
    int q  = t & 3;         // which float4 of the 16-float row
    int rg = t >> 2;        // 0..63 row group
    float4 acc = make_float4(0.f, 0.f, 0.f, 0.f);
    const int jbase = k * RATIO_;
    #pragma unroll
    for (int m = 0; m < 4; ++m) {
        int n = P[jbase + rg + 64 * m];
        const float4* row =
            reinterpret_cast<const float4*>(x + ((size_t)(b * N_ + n)) * DIN_);
        float4 v = row[q];
        acc.x += v.x; acc.y += v.y; acc.z += v.z; acc.w += v.w;
    }
    // butterfly reduce over row-groups within the wave (bits 2..5 of lane id)
    #pragma unroll
    for (int mask = 4; mask <= 32; mask <<= 1) {
        acc.x += __shfl_xor(acc.x, mask, 64);
        acc.y += __shfl_xor(acc.y, mask, 64);
        acc.z += __shfl_xor(acc.z, mask, 64);
        acc.w += __shfl_xor(acc.w, mask, 64);
    }
    __shared__ float4 part[4][4];  // [wave][q]
    int lane = t & 63, wave = t >> 6;
    if (lane < 4) part[wave][lane] = acc;  // lane == q for lanes 0..3
    __syncthreads();
    if (t < 16) {
        int qq = t >> 2, comp = t & 3;
        float v = 0.f;
        #pragma unroll
        for (int w = 0; w < 4; ++w) {
            const float* p = reinterpret_cast<const float*>(&part[w][qq]);
            v += p[comp];
        }
        int i = qq * 4 + comp;
        s[i * (B_ * C_) + b * C_ + k] = v;
    }
}

// ---------------------------------------------------------------------------
// Kernel B: off[b,c,o] = (1/N) * sum_{i,k} w_off[o,i,c,k] * s[b,k,i] + b1[o]
// grid = C_ * 4 blocks: (c, o-group of 4). thread t owns k = t.
// ---------------------------------------------------------------------------
__global__ __launch_bounds__(256) void k_off(
    const float* __restrict__ w_off, const float* __restrict__ s,
    const float* __restrict__ b1, float* __restrict__ off)
{
    int c  = blockIdx.x >> 2;
    int og = blockIdx.x & 3;
    int t  = threadIdx.x;  // k
    float acc[64];         // [b][o4]
    #pragma unroll
    for (int z = 0; z < 64; ++z) acc[z] = 0.f;

    for (int i = 0; i < DIN_; ++i) {
        float wv[4];
        #pragma unroll
        for (int o4 = 0; o4 < 4; ++o4) {
            int o = og * 4 + o4;
            wv[o4] = w_off[((size_t)((o * DIN_ + i) * C_ + c)) * C_ + t];
        }
        #pragma unroll
        for (int b = 0; b < B_; ++b) {
            float sv = s[i * (B_ * C_) + b * C_ + t];
            #pragma unroll
            for (int o4 = 0; o4 < 4; ++o4) acc[b * 4 + o4] += wv[o4] * sv;
        }
    }

    // block reduction over k (256 threads), 8 outputs per round
    __shared__ float red[8][256];
    const float invN = 1.0f / (float)N_;
    #pragma unroll
    for (int rd = 0; rd < 8; ++rd) {
        __syncthreads();
        #pragma unroll
        for (int oo = 0; oo < 8; ++oo) red[oo][t] = acc[rd * 8 + oo];
        __syncthreads();
        int grp = t >> 5;   // which of the 8 outputs
        int seg = t & 31;
        float p = 0.f;
        #pragma unroll
        for (int j = 0; j < 8; ++j) p += red[grp][seg * 8 + j];
        #pragma unroll
        for (int d = 16; d > 0; d >>= 1) p += __shfl_down(p, d, 32);
        if (seg == 0) {
            int outid = rd * 8 + grp;
            int b  = outid >> 2, o4 = outid & 3;
            int o  = og * 4 + o4;
            off[((b << 8) + c) * DOUT_ + o] = p * invN + b1[o];
        }
    }
}

// ---------------------------------------------------------------------------
// Kernel C: out[b, P[j], :] = wd_t[c]^T-applied mat-vec + off[b,c,:]
// grid = B_*C_ blocks (b, cluster). thread t -> j = c*256 + t.
// ---------------------------------------------------------------------------
__global__ __launch_bounds__(256) void k_apply(
    const float* __restrict__ x, const int* __restrict__ P,
    const float* __restrict__ wd_t, const float* __restrict__ off,
    float* __restrict__ out)
{
    int bid = blockIdx.x;
    int b = bid >> 8, k = bid & (C_ - 1);
    int t = threadIdx.x;
    __shared__ float4 wds[64];   // wd[i][o] as float4 over o
    __shared__ float4 offs[4];
    reinterpret_cast<float*>(wds)[t] = wd_t[k * 256 + t];
    if (t < 16)
        reinterpret_cast<float*>(offs)[t] = off[((b << 8) + k) * DOUT_ + t];
    __syncthreads();

    int n = P[(k << 8) + t];
    const float4* row =
        reinterpret_cast<const float4*>(x + ((size_t)(b * N_ + n)) * DIN_);
    float4 x0 = row[0], x1 = row[1], x2 = row[2], x3 = row[3];
    float xv[16];
    xv[0]=x0.x; xv[1]=x0.y; xv[2]=x0.z; xv[3]=x0.w;
    xv[4]=x1.x; xv[5]=x1.y; xv[6]=x1.z; xv[7]=x1.w;
    xv[8]=x2.x; xv[9]=x2.y; xv[10]=x2.z; xv[11]=x2.w;
    xv[12]=x3.x; xv[13]=x3.y; xv[14]=x3.z; xv[15]=x3.w;

    float4 a0 = offs[0], a1 = offs[1], a2 = offs[2], a3 = offs[3];
    #pragma unroll
    for (int i = 0; i < 16; ++i) {
        float xi = xv[i];
        float4 w0 = wds[i * 4 + 0];
        float4 w1 = wds[i * 4 + 1];
        float4 w2 = wds[i * 4 + 2];
        float4 w3 = wds[i * 4 + 3];
        a0.x += xi * w0.x; a0.y += xi * w0.y; a0.z += xi * w0.z; a0.w += xi * w0.w;
        a1.x += xi * w1.x; a1.y += xi * w1.y; a1.z += xi * w1.z; a1.w += xi * w1.w;
        a2.x += xi * w2.x; a2.y += xi * w2.y; a2.z += xi * w2.z; a2.w += xi * w2.w;
        a3.x += xi * w3.x; a3.y += xi * w3.y; a3.z += xi * w3.z; a3.w += xi * w3.w;
    }
    float4* orow =
        reinterpret_cast<float4*>(out + ((size_t)(b * N_ + n)) * DOUT_);
    orow[0] = a0; orow[1] = a1; orow[2] = a2; orow[3] = a3;
}

extern "C" void kernel_launch(void* const* d_in, const int* in_sizes, int n_in,
                              void* d_out, int out_size, void* d_ws, size_t ws_size,
                              hipStream_t stream) {
    const float* x      = (const float*)d_in[0];
    const float* w_diag = (const float*)d_in[1];
    const float* w_off  = (const float*)d_in[2];
    const float* b1     = (const float*)d_in[3];
    const int*   P      = (const int*)d_in[4];
    float* out  = (float*)d_out;
    float* s    = (float*)d_ws;        // 65536 floats
    float* off  = s + 65536;           // 65536 floats
    float* wd_t = off + 65536;         // 65536 floats

    k_cluster_sum<<<B_ * C_ + C_, 256, 0, stream>>>(x, w_diag, P, s, wd_t);
    k_off<<<C_ * 4, 256, 0, stream>>>(w_off, s, b1, off);
    k_apply<<<B_ * C_, 256, 0, stream>>>(x, P, wd_t, off, out);
}

// Round 2
// 226.646 us; speedup vs baseline: 1.0149x; 1.0149x over previous
//
#include <hip/hip_runtime.h>

#define B_    16
#define N_    65536
#define C_    256
#define DIN_  16
#define DOUT_ 16
#define RATIO_ 256  // N_/C_

// workspace layout:
//   s      [DIN_][B_][C_]    = 65536 floats  (s[i][b][k])
//   off    [B_][C_][DOUT_]   = 65536 floats  (includes /N and +b1)
//   wd_t   [C_][DIN_*DOUT_]  = 65536 floats  (wd_t[c][i*16+o])
//   c_of_n [N_]              = 65536 ints    (cluster id of source row n)

// ---------------------------------------------------------------------------
// K0: prep. blocks 0..255: transpose w_diag[o][i][c] -> wd_t[c][i*16+o]
//     blocks 256..511: c_of_n[P[j]] = j>>8
// ---------------------------------------------------------------------------
__global__ __launch_bounds__(256) void k_prep(
    const float* __restrict__ w_diag, const int* __restrict__ P,
    float* __restrict__ wd_t, int* __restrict__ c_of_n)
{
    int t = threadIdx.x;
    int bid = blockIdx.x;
    if (bid < 256) {
        int o = bid >> 4, i = bid & 15;
        float v = w_diag[(o * DIN_ + i) * C_ + t];   // coalesced read (t = c)
        wd_t[t * 256 + i * 16 + o] = v;              // scattered write, L2
    } else {
        int k = bid - 256;
        int j = k * 256 + t;
        c_of_n[P[j]] = k;
    }
}

// ---------------------------------------------------------------------------
// K1: fused gather. block = (b, cluster k). thread t -> j = k*256+t, n = P[j].
// Reads x row ONCE: computes cluster sum s[b,k,:] AND writes diag matvec
// (no bias, no off yet) to out[b,n,:].
// ---------------------------------------------------------------------------
__global__ __launch_bounds__(256) void k_main(
    const float* __restrict__ x, const int* __restrict__ P,
    const float* __restrict__ wd_t, float* __restrict__ s,
    float* __restrict__ out)
{
    int bid = blockIdx.x;
    int b = bid >> 8, k = bid & (C_ - 1);
    int t = threadIdx.x;
    __shared__ float4 wds[64];     // wd[i][o] as float4 over o
    __shared__ float4 part[4][4];  // [wave][q] partial cluster sums

    reinterpret_cast<float*>(wds)[t] = wd_t[k * 256 + t];  // coalesced, L2-hit

    int n = P[(k << 8) + t];
    const float4* row =
        reinterpret_cast<const float4*>(x + ((size_t)(b * N_ + n)) * DIN_);
    float4 x0 = row[0], x1 = row[1], x2 = row[2], x3 = row[3];
    __syncthreads();

    // ---- diag matvec: out_diag = wd^T-applied row ----
    float xv[16];
    xv[0]=x0.x; xv[1]=x0.y; xv[2]=x0.z; xv[3]=x0.w;
    xv[4]=x1.x; xv[5]=x1.y; xv[6]=x1.z; xv[7]=x1.w;
    xv[8]=x2.x; xv[9]=x2.y; xv[10]=x2.z; xv[11]=x2.w;
    xv[12]=x3.x; xv[13]=x3.y; xv[14]=x3.z; xv[15]=x3.w;

    float4 a0 = make_float4(0.f,0.f,0.f,0.f), a1 = a0, a2 = a0, a3 = a0;
    #pragma unroll
    for (int i = 0; i < 16; ++i) {
        float xi = xv[i];
        float4 w0 = wds[i * 4 + 0];
        float4 w1 = wds[i * 4 + 1];
        float4 w2 = wds[i * 4 + 2];
        float4 w3 = wds[i * 4 + 3];
        a0.x += xi * w0.x; a0.y += xi * w0.y; a0.z += xi * w0.z; a0.w += xi * w0.w;
        a1.x += xi * w1.x; a1.y += xi * w1.y; a1.z += xi * w1.z; a1.w += xi * w1.w;
        a2.x += xi * w2.x; a2.y += xi * w2.y; a2.z += xi * w2.z; a2.w += xi * w2.w;
        a3.x += xi * w3.x; a3.y += xi * w3.y; a3.z += xi * w3.z; a3.w += xi * w3.w;
    }
    float4* orow =
        reinterpret_cast<float4*>(out + ((size_t)(b * N_ + n)) * DOUT_);
    orow[0] = a0; orow[1] = a1; orow[2] = a2; orow[3] = a3;

    // ---- cluster sum: reduce x-rows across the 256 threads ----
    // butterfly masks 1,2 on all 16 components (after this, each quad of
    // lanes holds identical 4-row sums)
    #pragma unroll
    for (int mask = 1; mask <= 2; mask <<= 1) {
        x0.x += __shfl_xor(x0.x, mask, 64); x0.y += __shfl_xor(x0.y, mask, 64);
        x0.z += __shfl_xor(x0.z, mask, 64); x0.w += __shfl_xor(x0.w, mask, 64);
        x1.x += __shfl_xor(x1.x, mask, 64); x1.y += __shfl_xor(x1.y, mask, 64);
        x1.z += __shfl_xor(x1.z, mask, 64); x1.w += __shfl_xor(x1.w, mask, 64);
        x2.x += __shfl_xor(x2.x, mask, 64); x2.y += __shfl_xor(x2.y, mask, 64);
        x2.z += __shfl_xor(x2.z, mask, 64); x2.w += __shfl_xor(x2.w, mask, 64);
        x3.x += __shfl_xor(x3.x, mask, 64); x3.y += __shfl_xor(x3.y, mask, 64);
        x3.z += __shfl_xor(x3.z, mask, 64); x3.w += __shfl_xor(x3.w, mask, 64);
    }
    // each lane keeps the float4 matching its quad position
    int q = t & 3;
    float4 v = (q == 0) ? x0 : (q == 1) ? x1 : (q == 2) ? x2 : x3;
    #pragma unroll
    for (int mask = 4; mask <= 32; mask <<= 1) {
        v.x += __shfl_xor(v.x, mask, 64);
        v.y += __shfl_xor(v.y, mask, 64);
        v.z += __shfl_xor(v.z, mask, 64);
        v.w += __shfl_xor(v.w, mask, 64);
    }
    int lane = t & 63, wave = t >> 6;
    if (lane < 4) part[wave][lane] = v;   // lane == q for lanes 0..3
    __syncthreads();
    if (t < 16) {
        int qq = t >> 2, comp = t & 3;
        float sv = 0.f;
        #pragma unroll
        for (int w = 0; w < 4; ++w) {
            const float* p = reinterpret_cast<const float*>(&part[w][qq]);
            sv += p[comp];
        }
        int i = qq * 4 + comp;
        s[i * (B_ * C_) + b * C_ + k] = sv;
    }
}

// ---------------------------------------------------------------------------
// K2: off[b,c,o] = (1/N) * sum_{i,k} w_off[o,i,c,k] * s[b,k,i] + b1[o]
// grid = C_ * 4 blocks: (c, o-group of 4). thread t owns k = t.
// ---------------------------------------------------------------------------
__global__ __launch_bounds__(256) void k_off(
    const float* __restrict__ w_off, const float* __restrict__ s,
    const float* __restrict__ b1, float* __restrict__ off)
{
    int c  = blockIdx.x >> 2;
    int og = blockIdx.x & 3;
    int t  = threadIdx.x;  // k
    float acc[64];         // [b][o4]
    #pragma unroll
    for (int z = 0; z < 64; ++z) acc[z] = 0.f;

    for (int i = 0; i < DIN_; ++i) {
        float wv[4];
        #pragma unroll
        for (int o4 = 0; o4 < 4; ++o4) {
            int o = og * 4 + o4;
            wv[o4] = w_off[((size_t)((o * DIN_ + i) * C_ + c)) * C_ + t];
        }
        #pragma unroll
        for (int b = 0; b < B_; ++b) {
            float sv = s[i * (B_ * C_) + b * C_ + t];
            #pragma unroll
            for (int o4 = 0; o4 < 4; ++o4) acc[b * 4 + o4] += wv[o4] * sv;
        }
    }

    __shared__ float red[8][256];
    const float invN = 1.0f / (float)N_;
    #pragma unroll
    for (int rd = 0; rd < 8; ++rd) {
        __syncthreads();
        #pragma unroll
        for (int oo = 0; oo < 8; ++oo) red[oo][t] = acc[rd * 8 + oo];
        __syncthreads();
        int grp = t >> 5;
        int seg = t & 31;
        float p = 0.f;
        #pragma unroll
        for (int j = 0; j < 8; ++j) p += red[grp][seg * 8 + j];
        #pragma unroll
        for (int d = 16; d > 0; d >>= 1) p += __shfl_down(p, d, 32);
        if (seg == 0) {
            int outid = rd * 8 + grp;
            int b  = outid >> 2, o4 = outid & 3;
            int o  = og * 4 + o4;
            off[((b << 8) + c) * DOUT_ + o] = p * invN + b1[o];
        }
    }
}

// ---------------------------------------------------------------------------
// K3: sequential fix-up: out[b,n,:] += off[b, c_of_n[n], :]
// thread = one float4 of out. Fully coalesced on out; off/c_of_n L2-resident.
// ---------------------------------------------------------------------------
__global__ __launch_bounds__(256) void k_add_off(
    const int* __restrict__ c_of_n, const float* __restrict__ off,
    float* __restrict__ out)
{
    size_t g = (size_t)blockIdx.x * 256 + threadIdx.x;  // float4 index
    int rowid = (int)(g >> 2);       // b*65536 + n
    int b = rowid >> 16;
    int n = rowid & 65535;
    int q = (int)(g & 3);
    int c = c_of_n[n];
    const float4* offp =
        reinterpret_cast<const float4*>(off + (size_t)(((b << 8) + c) * DOUT_));
    float4 o4 = offp[q];
    float4* op = reinterpret_cast<float4*>(out) + g;
    float4 v = *op;
    v.x += o4.x; v.y += o4.y; v.z += o4.z; v.w += o4.w;
    *op = v;
}

extern "C" void kernel_launch(void* const* d_in, const int* in_sizes, int n_in,
                              void* d_out, int out_size, void* d_ws, size_t ws_size,
                              hipStream_t stream) {
    const float* x      = (const float*)d_in[0];
    const float* w_diag = (const float*)d_in[1];
    const float* w_off  = (const float*)d_in[2];
    const float* b1     = (const float*)d_in[3];
    const int*   P      = (const int*)d_in[4];
    float* out    = (float*)d_out;
    float* s      = (float*)d_ws;          // 65536 floats
    float* off    = s + 65536;             // 65536 floats
    float* wd_t   = off + 65536;           // 65536 floats
    int*   c_of_n = (int*)(wd_t + 65536);  // 65536 ints

    k_prep<<<512, 256, 0, stream>>>(w_diag, P, wd_t, c_of_n);
    k_main<<<B_ * C_, 256, 0, stream>>>(x, P, wd_t, s, out);
    k_off<<<C_ * 4, 256, 0, stream>>>(w_off, s, b1, off);
    k_add_off<<<(B_ * N_ * DOUT_ / 4) / 256, 256, 0, stream>>>(c_of_n, off, out);
}